// Round 1
// baseline (4591.287 us; speedup 1.0000x reference)
//
#include <hip/hip_runtime.h>

typedef short bf16x8 __attribute__((ext_vector_type(8)));
typedef float f32x4 __attribute__((ext_vector_type(4)));
typedef unsigned short us8 __attribute__((ext_vector_type(8)));

#define B_ 256
#define T_ 1024
#define H_ 512
#define E_ 256
#define O_ 256
#define V_ 256

// Prepped operands live in device globals: no ws_size assumptions, graph-safe,
// rewritten deterministically every launch.
__device__ __align__(16) unsigned short g_P[V_ * H_];     // P = emb@Wx^T + b, bf16 (256 KB)
__device__ __align__(16) unsigned short g_Whf[H_ * H_];   // Wh in MFMA B-frag layout (512 KB)
__device__ __align__(16) unsigned short g_Wdf[O_ * H_];   // Wd in MFMA B-frag layout (256 KB)

__device__ __forceinline__ unsigned short f2bf(float f) {
    union { float f; unsigned int u; } v; v.f = f;
    unsigned int r = v.u + 0x7fffu + ((v.u >> 16) & 1u);   // RNE
    return (unsigned short)(r >> 16);
}
__device__ __forceinline__ float bf2f(unsigned short s) {
    union { unsigned int u; float f; } v; v.u = ((unsigned int)s) << 16;
    return v.f;
}

// ---------------- K1a: P[v][n] = b[n] + sum_e emb[v][e] * Wx[n][e] ----------------
__global__ void k_embWx(const float* __restrict__ emb, const float* __restrict__ W,
                        const float* __restrict__ bb) {
    __shared__ float e[E_];
    int v = blockIdx.x;
    e[threadIdx.x] = emb[(size_t)v * E_ + threadIdx.x];
    __syncthreads();
#pragma unroll
    for (int rep = 0; rep < 2; rep++) {
        int n = threadIdx.x + rep * 256;
        const float4* wr4 = (const float4*)(W + (size_t)n * (E_ + H_));  // Wx row = W[n][0:256]
        float s = bb[n];
        for (int k = 0; k < E_ / 4; k++) {
            float4 wv = wr4[k];
            s += e[4*k] * wv.x + e[4*k+1] * wv.y + e[4*k+2] * wv.z + e[4*k+3] * wv.w;
        }
        g_P[v * H_ + n] = f2bf(s);
    }
}

// ---------------- K1b/K1c: weight -> MFMA B-fragment layout (bf16) ----------------
// Tile (nt,kt): lane l, elem j holds  Wmat[n = nt*16 + (l&15)][k = kt*32 + (l>>4)*8 + j]
__global__ void k_fragWh(const float* __restrict__ W) {
    int gid = blockIdx.x * blockDim.x + threadIdx.x;   // 512 tiles * 64 lanes
    int l = gid & 63, tile = gid >> 6;
    int kt = tile & 15, nt = tile >> 4;
    int n = nt * 16 + (l & 15), k0 = kt * 32 + (l >> 4) * 8;
    const float* src = W + (size_t)n * (E_ + H_) + E_ + k0;   // Wh = W[:,256:]
#pragma unroll
    for (int j = 0; j < 8; j++) g_Whf[(size_t)gid * 8 + j] = f2bf(src[j]);
}
__global__ void k_fragWd(const float* __restrict__ Wd) {
    int gid = blockIdx.x * blockDim.x + threadIdx.x;   // 256 tiles * 64 lanes
    int l = gid & 63, tile = gid >> 6;
    int kt = tile & 15, nt = tile >> 4;
    int n = nt * 16 + (l & 15), k0 = kt * 32 + (l >> 4) * 8;
    const float* src = Wd + (size_t)n * H_ + k0;
#pragma unroll
    for (int j = 0; j < 8; j++) g_Wdf[(size_t)gid * 8 + j] = f2bf(src[j]);
}

// ---------------- K2: recurrence, Wh fully pinned on-CU ----------------
// 16 blocks x 16 batch rows; 8 waves; wave w owns n-tiles 4w..4w+3 (64 outputs).
// B-frags kt 0..11 in 192 VGPRs, kt 12..15 in 128 KB LDS. h (bf16) + u staged in LDS,
// XOR-swizzled (byte ^= (row&7)<<4) to kill the 32-way row-major bank conflict (G4).
__launch_bounds__(512, 2)
__global__ void k_rnn(const int* __restrict__ x, const float* __restrict__ h0,
                      float* __restrict__ out) {
    __shared__ __align__(16) unsigned short lds_h[16 * 512];    // 16 KB
    __shared__ __align__(16) unsigned short lds_u[16 * 512];    // 16 KB
    __shared__ __align__(16) unsigned short lds_B[128 * 512];   // 128 KB
    int tid = threadIdx.x;
    int w = tid >> 6, l = tid & 63;
    int hi = l >> 4, lo = l & 15;
    int r0 = blockIdx.x * 16;

    // pinned B-fragments, kt 0..11  (4 ntiles x 12 = 48 frags = 192 VGPRs)
    bf16x8 breg[4][12];
#pragma unroll
    for (int nt = 0; nt < 4; nt++)
#pragma unroll
        for (int kt = 0; kt < 12; kt++)
            breg[nt][kt] = *(const bf16x8*)(g_Whf + (size_t)((4*w + nt) * 16 + kt) * 512 + l * 8);

    // LDS-pinned B-fragments, kt 12..15
#pragma unroll
    for (int nt = 0; nt < 4; nt++)
#pragma unroll
        for (int kk = 0; kk < 4; kk++) {
            bf16x8 v = *(const bf16x8*)(g_Whf + (size_t)((4*w + nt) * 16 + 12 + kk) * 512 + l * 8);
            *(bf16x8*)((char*)lds_B + (w * 16 + nt * 4 + kk) * 1024 + l * 16) = v;
        }

    // stage h0 (fp32 -> bf16, swizzled)
    {
        int row = tid >> 5;
        int c = (tid & 31) * 16;
        const float* hsrc = h0 + (size_t)(r0 + row) * H_ + c;
        us8 va, vb;
#pragma unroll
        for (int i = 0; i < 8; i++) ((unsigned short*)&va)[i] = f2bf(hsrc[i]);
#pragma unroll
        for (int i = 0; i < 8; i++) ((unsigned short*)&vb)[i] = f2bf(hsrc[8 + i]);
        char* hb = (char*)lds_h + row * 1024;
        int cb = c * 2;
        *(us8*)(hb + ((cb)      ^ ((row & 7) << 4))) = va;
        *(us8*)(hb + ((cb + 16) ^ ((row & 7) << 4))) = vb;
    }
    __syncthreads();

    unsigned short* hs = (unsigned short*)out;            // hs[b,t] bf16 in-place in d_out
    float* hfin = out + (size_t)B_ * T_ * O_;             // h_final fp32

#pragma unroll 1
    for (int t = 0; t < T_; t++) {
        // phase A: stage u = P[x[r,t]]  (wave w stages rows 2w, 2w+1)
        {
            int rl = 2 * w + (l >> 5);
            int xv = x[(size_t)(r0 + rl) * T_ + t];
            const unsigned short* src = g_P + (size_t)xv * H_ + (l & 31) * 16;
            us8 v0 = *(const us8*)(src);
            us8 v1 = *(const us8*)(src + 8);
            char* ub = (char*)lds_u + rl * 1024;
            int cb = (l & 31) * 32;
            *(us8*)(ub + ((cb)      ^ ((rl & 7) << 4))) = v0;
            *(us8*)(ub + ((cb + 16) ^ ((rl & 7) << 4))) = v1;
        }
        // phase B: acc = h @ Wh^T  (A-frag rows from lds_h, B-frags reg/LDS)
        f32x4 acc[4];
#pragma unroll
        for (int nt = 0; nt < 4; nt++) { acc[nt][0] = 0.f; acc[nt][1] = 0.f; acc[nt][2] = 0.f; acc[nt][3] = 0.f; }
#pragma unroll
        for (int kt = 0; kt < 16; kt++) {
            const bf16x8 a = *(const bf16x8*)((const char*)lds_h + lo * 1024 +
                                              ((kt * 64 + hi * 16) ^ ((lo & 7) << 4)));
#pragma unroll
            for (int nt = 0; nt < 4; nt++) {
                bf16x8 bf;
                if (kt < 12) bf = breg[nt][kt];
                else bf = *(const bf16x8*)((const char*)lds_B + (w * 16 + nt * 4 + (kt - 12)) * 1024 + l * 16);
                acc[nt] = __builtin_amdgcn_mfma_f32_16x16x32_bf16(a, bf, acc[nt], 0, 0, 0);
            }
        }
        __syncthreads();   // #1: all h-reads done, u-stage visible
        // phase D: epilogue  h_next = tanh(acc + u); write hs, lds_h
#pragma unroll
        for (int nt = 0; nt < 4; nt++) {
            int n = (4 * w + nt) * 16 + lo;
#pragma unroll
            for (int rg = 0; rg < 4; rg++) {
                int r = hi * 4 + rg;                       // C/D row = (lane>>4)*4 + reg  [m89]
                float u = bf2f(*(const unsigned short*)((const char*)lds_u + r * 1024 +
                                                        ((2 * n) ^ ((r & 7) << 4))));
                float vv = acc[nt][rg] + u;
                float ex = __expf(vv + vv);
                float th = 1.f - __fdividef(2.f, ex + 1.f);   // tanh
                hs[(size_t)((r0 + r) * T_ + t) * H_ + n] = f2bf(th);
                if (t == T_ - 1) hfin[(size_t)(r0 + r) * H_ + n] = th;
                *(unsigned short*)((char*)lds_h + r * 1024 + ((2 * n) ^ ((r & 7) << 4))) = f2bf(th);
            }
        }
        __syncthreads();   // #2: h_next visible for next step
    }
}

// ---------------- K3: outputs = hs @ Wd^T + bd, in-place over hs slots ----------------
// 1024 blocks x 256 (b,t)-rows; wave w: 32 rows x all 256 outs. Reads bf16 hs from the
// exact d_out bytes it later overwrites with fp32 outputs (reads precede writes per wave).
__launch_bounds__(512, 2)
__global__ void k_out(const float* __restrict__ bd, float* out) {
    int tid = threadIdx.x;
    int w = tid >> 6, l = tid & 63;
    int hi = l >> 4, lo = l & 15;
    size_t m0 = (size_t)blockIdx.x * 256 + w * 32;
    const unsigned short* hsb = (const unsigned short*)out;
    float bdv[16];
#pragma unroll
    for (int nt = 0; nt < 16; nt++) bdv[nt] = bd[nt * 16 + lo];
    f32x4 acc[2][16];
#pragma unroll
    for (int m = 0; m < 2; m++)
#pragma unroll
        for (int nt = 0; nt < 16; nt++) { acc[m][nt][0] = 0.f; acc[m][nt][1] = 0.f; acc[m][nt][2] = 0.f; acc[m][nt][3] = 0.f; }
#pragma unroll 2
    for (int kt = 0; kt < 16; kt++) {
        bf16x8 a0 = *(const bf16x8*)(hsb + (m0 + lo) * 512 + kt * 32 + hi * 8);
        bf16x8 a1 = *(const bf16x8*)(hsb + (m0 + 16 + lo) * 512 + kt * 32 + hi * 8);
#pragma unroll
        for (int nt = 0; nt < 16; nt++) {
            bf16x8 bf = *(const bf16x8*)(g_Wdf + (size_t)(nt * 16 + kt) * 512 + l * 8);
            acc[0][nt] = __builtin_amdgcn_mfma_f32_16x16x32_bf16(a0, bf, acc[0][nt], 0, 0, 0);
            acc[1][nt] = __builtin_amdgcn_mfma_f32_16x16x32_bf16(a1, bf, acc[1][nt], 0, 0, 0);
        }
    }
#pragma unroll
    for (int m = 0; m < 2; m++)
#pragma unroll
        for (int nt = 0; nt < 16; nt++)
#pragma unroll
            for (int rg = 0; rg < 4; rg++) {
                size_t row = m0 + m * 16 + hi * 4 + rg;
                out[row * O_ + nt * 16 + lo] = acc[m][nt][rg] + bdv[nt];
            }
}

extern "C" void kernel_launch(void* const* d_in, const int* in_sizes, int n_in,
                              void* d_out, int out_size, void* d_ws, size_t ws_size,
                              hipStream_t stream) {
    const int*   x   = (const int*)d_in[0];
    const float* h0  = (const float*)d_in[1];
    const float* emb = (const float*)d_in[2];
    const float* W   = (const float*)d_in[3];
    const float* b   = (const float*)d_in[4];
    const float* Wd  = (const float*)d_in[5];
    const float* bd  = (const float*)d_in[6];
    float* out = (float*)d_out;

    k_embWx<<<dim3(V_), dim3(256), 0, stream>>>(emb, W, b);
    k_fragWh<<<dim3(128), dim3(256), 0, stream>>>(W);
    k_fragWd<<<dim3(64), dim3(256), 0, stream>>>(Wd);
    k_rnn<<<dim3(16), dim3(512), 0, stream>>>(x, h0, out);
    k_out<<<dim3(1024), dim3(512), 0, stream>>>(bd, out);
}